// Round 3
// baseline (1952.600 us; speedup 1.0000x reference)
//
#include <hip/hip_runtime.h>

#define DDIM 64
constexpr int U_CNT = 100000;
constexpr int I_CNT = 50000;
constexpr int N_CNT = U_CNT + I_CNT;          // 150000
constexpr int NB    = N_CNT + U_CNT + I_CNT;  // 300000 output rows

constexpr int BIN_ROWS_LOG = 8;
constexpr int BIN_ROWS = 1 << BIN_ROWS_LOG;               // 256 rows / bin
constexpr int BINS = (NB + BIN_ROWS - 1) / BIN_ROWS;      // 1172
constexpr int BINS_PAD = 1536;                            // 512 thr * 3 slots
constexpr int SORT_EDGES = 4096;                          // edges per binsort block
constexpr int HIST_EDGES = 8192;                          // edges per hist block

__device__ __forceinline__ int wave_incl_scan(int v, int lane) {
#pragma unroll
    for (int off = 1; off < 64; off <<= 1) {
        int t = __shfl_up(v, off, 64);
        if (lane >= off) v += t;
    }
    return v;
}

// ---- pass 0: coarse histogram over 1172 bins (LDS hist + flush) ----
__global__ __launch_bounds__(1024) void hist_pre(const int* __restrict__ gr,
                                                 const int* __restrict__ ur,
                                                 const int* __restrict__ ir,
                                                 int EG, int EU, int EI,
                                                 int* __restrict__ cnt) {
    __shared__ int h[BINS_PAD];
    for (int i = threadIdx.x; i < BINS_PAD; i += 1024) h[i] = 0;
    __syncthreads();
    int base = blockIdx.x * HIST_EDGES;
    int Et = EG + EU + EI;
#pragma unroll
    for (int j = 0; j < 8; ++j) {
        int e = base + j * 1024 + threadIdx.x;
        if (e < Et) {
            int b;
            if (e < EG)           b = gr[e];
            else if (e < EG + EU) b = N_CNT + ur[e - EG];
            else                  b = N_CNT + U_CNT + ir[e - EG - EU];
            atomicAdd(&h[b >> BIN_ROWS_LOG], 1);
        }
    }
    __syncthreads();
    for (int i = threadIdx.x; i < BINS; i += 1024) {
        int v = h[i];
        if (v) atomicAdd(&cnt[i], v);
    }
}

// ---- pass 0b: exclusive scan of 1172 bin counts (single block) ----
__global__ __launch_bounds__(1024) void scan_bins(const int* __restrict__ cnt,
                                                  int* __restrict__ bin_base,
                                                  int* __restrict__ bin_cursor,
                                                  int E_total) {
    __shared__ int wsum[16], woff[16];
    int tid = threadIdx.x, lane = tid & 63, wid = tid >> 6;
    int i0 = 2 * tid, i1 = 2 * tid + 1;
    int c0 = (i0 < BINS) ? cnt[i0] : 0;
    int c1 = (i1 < BINS) ? cnt[i1] : 0;
    int v = c0 + c1;
    int incl = wave_incl_scan(v, lane);
    if (lane == 63) wsum[wid] = incl;
    __syncthreads();
    if (wid == 0 && lane < 16) {
        int s = wsum[lane], si = s;
#pragma unroll
        for (int off = 1; off < 16; off <<= 1) {
            int t = __shfl_up(si, off, 64);
            if (lane >= off) si += t;
        }
        woff[lane] = si - s;
    }
    __syncthreads();
    int e = incl - v + woff[wid];
    if (i0 < BINS) { bin_base[i0] = e;      bin_cursor[i0] = e; }
    if (i1 < BINS) { bin_base[i1] = e + c0; bin_cursor[i1] = e + c0; }
    if (tid == 0) bin_base[BINS] = E_total;
}

// ---- pass 1: block-local counting sort by bin, coalesced write to pool ----
// entry: lo = (row_local<<18) | gidx   (row_local<256, gidx<150K<2^18), hi = val bits
__global__ __launch_bounds__(512) void binsort(const int* __restrict__ rows,
                                               const int* __restrict__ cols,
                                               const float* __restrict__ vals, int E,
                                               int bucket_base, int gidx_base,
                                               int* __restrict__ bin_cursor,
                                               uint2* __restrict__ pool) {
    __shared__ uint2 sorted[SORT_EDGES];          // 32 KB
    __shared__ unsigned short sbin[SORT_EDGES];   // 8 KB
    __shared__ int hist[BINS_PAD];                // 6 KB (becomes global base)
    __shared__ int lscan[BINS_PAD];               // 6 KB
    __shared__ int lcur[BINS_PAD];                // 6 KB
    __shared__ int wsum[8], woff[8];

    int tid = threadIdx.x, lane = tid & 63, wid = tid >> 6;
    for (int i = tid; i < BINS_PAD; i += 512) { hist[i] = 0; lcur[i] = 0; }
    __syncthreads();

    int start = blockIdx.x * SORT_EDGES;
    int myb[8]; unsigned mylo[8]; float myv[8];
#pragma unroll
    for (int j = 0; j < 8; ++j) {
        int e = start + j * 512 + tid;
        if (e < E) {
            int bucket = bucket_base + rows[e];
            int gidx = gidx_base + cols[e];
            myb[j] = bucket >> BIN_ROWS_LOG;
            mylo[j] = ((unsigned)(bucket & (BIN_ROWS - 1)) << 18) | (unsigned)gidx;
            myv[j] = vals[e];
            atomicAdd(&hist[myb[j]], 1);
        } else myb[j] = -1;
    }
    __syncthreads();

    // local exclusive scan, 3 slots/thread over BINS_PAD
    int s0 = 3 * tid, s1 = s0 + 1, s2 = s0 + 2;
    int h0 = hist[s0], h1 = hist[s1], h2 = hist[s2];
    int v = h0 + h1 + h2;
    int incl = wave_incl_scan(v, lane);
    if (lane == 63) wsum[wid] = incl;
    __syncthreads();
    if (wid == 0 && lane < 8) {
        int s = wsum[lane], si = s;
#pragma unroll
        for (int off = 1; off < 8; off <<= 1) {
            int t = __shfl_up(si, off, 64);
            if (lane >= off) si += t;
        }
        woff[lane] = si - s;
    }
    __syncthreads();
    int e0 = incl - v + woff[wid];
    lscan[s0] = e0; lscan[s1] = e0 + h0; lscan[s2] = e0 + h0 + h1;
    // reserve global space per bin; overwrite hist with the global base
    if (s0 < BINS && h0) hist[s0] = atomicAdd(&bin_cursor[s0], h0);
    if (s1 < BINS && h1) hist[s1] = atomicAdd(&bin_cursor[s1], h1);
    if (s2 < BINS && h2) hist[s2] = atomicAdd(&bin_cursor[s2], h2);
    __syncthreads();

    // scatter into LDS, bin-sorted
#pragma unroll
    for (int j = 0; j < 8; ++j) {
        if (myb[j] >= 0) {
            int p = lscan[myb[j]] + atomicAdd(&lcur[myb[j]], 1);
            sorted[p] = make_uint2(mylo[j], __float_as_uint(myv[j]));
            sbin[p] = (unsigned short)myb[j];
        }
    }
    __syncthreads();

    // coalesced-ish write-out: consecutive pos -> consecutive global addrs per bin run
    int cntE = min(SORT_EDGES, E - start);
    for (int pos = tid; pos < cntE; pos += 512) {
        int b = sbin[pos];
        pool[hist[b] + (pos - lscan[b])] = sorted[pos];
    }
}

// ---- pass 2: one block per bin, LDS accumulator, atomic-free global ----
__global__ __launch_bounds__(512) void accum_bins(const int* __restrict__ bin_base,
                                                  const uint2* __restrict__ pool,
                                                  const float* __restrict__ user_emb,
                                                  const float* __restrict__ item_emb,
                                                  float* __restrict__ out) {
    __shared__ float acc[BIN_ROWS * DDIM];  // 64 KB
    int tid = threadIdx.x, lane = tid & 63, wid = tid >> 6;  // 8 waves
    int g = blockIdx.x;
    for (int i = tid; i < BIN_ROWS * DDIM; i += 512) acc[i] = 0.f;
    __syncthreads();

    int s = bin_base[g], e = bin_base[g + 1];
    int cnt = e - s;
    int k  = s + (int)(((long long)cnt * wid) >> 3);
    int kE = s + (int)(((long long)cnt * (wid + 1)) >> 3);

    auto gather = [&](unsigned gi) -> float {
        return (gi < (unsigned)U_CNT) ? user_emb[(size_t)gi * DDIM + lane]
                                      : item_emb[(size_t)(gi - U_CNT) * DDIM + lane];
    };

    for (; k + 4 <= kE; k += 4) {
        uint2 p0 = pool[k], p1 = pool[k + 1], p2 = pool[k + 2], p3 = pool[k + 3];
        unsigned r0 = p0.x >> 18, g0 = p0.x & 0x3FFFFu;
        unsigned r1 = p1.x >> 18, g1 = p1.x & 0x3FFFFu;
        unsigned r2 = p2.x >> 18, g2 = p2.x & 0x3FFFFu;
        unsigned r3 = p3.x >> 18, g3 = p3.x & 0x3FFFFu;
        float x0 = gather(g0);
        float x1 = gather(g1);
        float x2 = gather(g2);
        float x3 = gather(g3);
        atomicAdd(&acc[r0 * DDIM + lane], __uint_as_float(p0.y) * x0);
        atomicAdd(&acc[r1 * DDIM + lane], __uint_as_float(p1.y) * x1);
        atomicAdd(&acc[r2 * DDIM + lane], __uint_as_float(p2.y) * x2);
        atomicAdd(&acc[r3 * DDIM + lane], __uint_as_float(p3.y) * x3);
    }
    for (; k < kE; ++k) {
        uint2 p = pool[k];
        unsigned r = p.x >> 18, gi = p.x & 0x3FFFFu;
        atomicAdd(&acc[r * DDIM + lane], __uint_as_float(p.y) * gather(gi));
    }
    __syncthreads();

    // coalesced float4 write-out, one write per output element
    constexpr int TOT4 = BIN_ROWS * DDIM / 4;  // 4096
    const float4* a4 = (const float4*)acc;
    float4* out4 = (float4*)out;
    long long rowbase = (long long)g * BIN_ROWS;
    for (int i4 = tid; i4 < TOT4; i4 += 512) {
        int row = i4 >> 4;  // 16 float4 per row
        if (rowbase + row < NB)
            out4[(long long)g * TOT4 + i4] = a4[i4];
    }
}

// ---------------- fallback (R1 atomic path) ----------------
__global__ void spmm_graph_kernel(const int* __restrict__ rows, const int* __restrict__ cols,
                                  const float* __restrict__ vals,
                                  const float* __restrict__ user_emb,
                                  const float* __restrict__ item_emb,
                                  float* __restrict__ out, int E) {
    long long idx = (long long)blockIdx.x * blockDim.x + threadIdx.x;
    int e = (int)(idx >> 6), d = (int)(idx & 63);
    if (e >= E) return;
    int r = rows[e], c = cols[e];
    float v = vals[e];
    float x = (c < U_CNT) ? user_emb[(long long)c * DDIM + d]
                          : item_emb[(long long)(c - U_CNT) * DDIM + d];
    atomicAdd(&out[(long long)r * DDIM + d], v * x);
}

__global__ void spmm_plain_kernel(const int* __restrict__ rows, const int* __restrict__ cols,
                                  const float* __restrict__ vals,
                                  const float* __restrict__ emb,
                                  float* __restrict__ out, int E) {
    long long idx = (long long)blockIdx.x * blockDim.x + threadIdx.x;
    int e = (int)(idx >> 6), d = (int)(idx & 63);
    if (e >= E) return;
    int r = rows[e], c = cols[e];
    float v = vals[e];
    atomicAdd(&out[(long long)r * DDIM + d], v * emb[(long long)c * DDIM + d]);
}

// ---------------- launch ----------------
extern "C" void kernel_launch(void* const* d_in, const int* in_sizes, int n_in,
                              void* d_out, int out_size, void* d_ws, size_t ws_size,
                              hipStream_t stream) {
    const float* user_emb = (const float*)d_in[0];
    const float* item_emb = (const float*)d_in[1];
    const int*   g_rows   = (const int*)d_in[2];
    const int*   g_cols   = (const int*)d_in[3];
    const float* g_vals   = (const float*)d_in[4];
    const int*   u_rows   = (const int*)d_in[5];
    const int*   u_cols   = (const int*)d_in[6];
    const float* u_vals   = (const float*)d_in[7];
    const int*   i_rows   = (const int*)d_in[8];
    const int*   i_cols   = (const int*)d_in[9];
    const float* i_vals   = (const float*)d_in[10];
    float* out = (float*)d_out;

    const int EG = in_sizes[2];
    const int EU = in_sizes[5];
    const int EI = in_sizes[8];
    const int Et = EG + EU + EI;

    // ws layout: cnt[BINS_PAD] | bin_base[BINS+1] | bin_cursor[BINS] | pool[Et]
    size_t off_base   = (size_t)BINS_PAD * sizeof(int);
    size_t off_cursor = off_base + (size_t)(BINS + 1) * sizeof(int);
    size_t off_pool   = (off_cursor + (size_t)BINS * sizeof(int) + 15) & ~(size_t)15;
    size_t needed     = off_pool + (size_t)Et * sizeof(uint2);

    if (ws_size >= needed) {
        int*   cnt        = (int*)d_ws;
        int*   bin_base   = (int*)((char*)d_ws + off_base);
        int*   bin_cursor = (int*)((char*)d_ws + off_cursor);
        uint2* pool       = (uint2*)((char*)d_ws + off_pool);

        hipMemsetAsync(cnt, 0, (size_t)BINS_PAD * sizeof(int), stream);

        unsigned hblocks = (unsigned)((Et + HIST_EDGES - 1) / HIST_EDGES);
        hist_pre<<<hblocks, 1024, 0, stream>>>(g_rows, u_rows, i_rows, EG, EU, EI, cnt);
        scan_bins<<<1, 1024, 0, stream>>>(cnt, bin_base, bin_cursor, Et);

        unsigned gb = (unsigned)((EG + SORT_EDGES - 1) / SORT_EDGES);
        unsigned ub = (unsigned)((EU + SORT_EDGES - 1) / SORT_EDGES);
        unsigned ib = (unsigned)((EI + SORT_EDGES - 1) / SORT_EDGES);
        binsort<<<gb, 512, 0, stream>>>(g_rows, g_cols, g_vals, EG, 0,             0,     bin_cursor, pool);
        binsort<<<ub, 512, 0, stream>>>(u_rows, u_cols, u_vals, EU, N_CNT,         0,     bin_cursor, pool);
        binsort<<<ib, 512, 0, stream>>>(i_rows, i_cols, i_vals, EI, N_CNT + U_CNT, U_CNT, bin_cursor, pool);

        accum_bins<<<BINS, 512, 0, stream>>>(bin_base, pool, user_emb, item_emb, out);
    } else {
        hipMemsetAsync(d_out, 0, (size_t)out_size * sizeof(float), stream);
        const int block = 256;
        {
            long long t = (long long)EG * DDIM;
            spmm_graph_kernel<<<(unsigned)((t + block - 1) / block), block, 0, stream>>>(
                g_rows, g_cols, g_vals, user_emb, item_emb, out, EG);
        }
        {
            long long t = (long long)EU * DDIM;
            spmm_plain_kernel<<<(unsigned)((t + block - 1) / block), block, 0, stream>>>(
                u_rows, u_cols, u_vals, user_emb, out + (size_t)N_CNT * DDIM, EU);
        }
        {
            long long t = (long long)EI * DDIM;
            spmm_plain_kernel<<<(unsigned)((t + block - 1) / block), block, 0, stream>>>(
                i_rows, i_cols, i_vals, item_emb, out + (size_t)(N_CNT + U_CNT) * DDIM, EI);
        }
    }
}

// Round 4
// 523.067 us; speedup vs baseline: 3.7330x; 3.7330x over previous
//
#include <hip/hip_runtime.h>

#define DDIM 64
constexpr int U_CNT = 100000;
constexpr int I_CNT = 50000;
constexpr int N_CNT = U_CNT + I_CNT;          // 150000
constexpr int NB    = N_CNT + U_CNT + I_CNT;  // 300000 output rows

constexpr int BIN_ROWS_LOG = 8;
constexpr int BIN_ROWS = 1 << BIN_ROWS_LOG;               // 256 rows / bin
constexpr int BINS = (NB + BIN_ROWS - 1) / BIN_ROWS;      // 1172
constexpr int BINS_PAD = 1536;                            // 512 thr * 3 slots
constexpr int SORT_EDGES = 4096;                          // edges per binsort block
constexpr int HIST_EDGES = 8192;                          // edges per hist block
constexpr int CAP = 6144;  // max edges per bin in refine (mean 4096, sigma 64 -> +32 sigma)

__device__ __forceinline__ int wave_incl_scan(int v, int lane) {
#pragma unroll
    for (int off = 1; off < 64; off <<= 1) {
        int t = __shfl_up(v, off, 64);
        if (lane >= off) v += t;
    }
    return v;
}

// ---- pass 0: coarse histogram over bins ----
__global__ __launch_bounds__(1024) void hist_pre(const int* __restrict__ gr,
                                                 const int* __restrict__ ur,
                                                 const int* __restrict__ ir,
                                                 int EG, int EU, int EI,
                                                 int* __restrict__ cnt) {
    __shared__ int h[BINS_PAD];
    for (int i = threadIdx.x; i < BINS_PAD; i += 1024) h[i] = 0;
    __syncthreads();
    int base = blockIdx.x * HIST_EDGES;
    int Et = EG + EU + EI;
#pragma unroll
    for (int j = 0; j < 8; ++j) {
        int e = base + j * 1024 + threadIdx.x;
        if (e < Et) {
            int b;
            if (e < EG)           b = gr[e];
            else if (e < EG + EU) b = N_CNT + ur[e - EG];
            else                  b = N_CNT + U_CNT + ir[e - EG - EU];
            atomicAdd(&h[b >> BIN_ROWS_LOG], 1);
        }
    }
    __syncthreads();
    for (int i = threadIdx.x; i < BINS; i += 1024) {
        int v = h[i];
        if (v) atomicAdd(&cnt[i], v);
    }
}

// ---- pass 0b: exclusive scan of bin counts (single block) ----
__global__ __launch_bounds__(1024) void scan_bins(const int* __restrict__ cnt,
                                                  int* __restrict__ bin_base,
                                                  int* __restrict__ bin_cursor,
                                                  int E_total) {
    __shared__ int wsum[16], woff[16];
    int tid = threadIdx.x, lane = tid & 63, wid = tid >> 6;
    int i0 = 2 * tid, i1 = 2 * tid + 1;
    int c0 = (i0 < BINS) ? cnt[i0] : 0;
    int c1 = (i1 < BINS) ? cnt[i1] : 0;
    int v = c0 + c1;
    int incl = wave_incl_scan(v, lane);
    if (lane == 63) wsum[wid] = incl;
    __syncthreads();
    if (wid == 0 && lane < 16) {
        int s = wsum[lane], si = s;
#pragma unroll
        for (int off = 1; off < 16; off <<= 1) {
            int t = __shfl_up(si, off, 64);
            if (lane >= off) si += t;
        }
        woff[lane] = si - s;
    }
    __syncthreads();
    int e = incl - v + woff[wid];
    if (i0 < BINS) { bin_base[i0] = e;      bin_cursor[i0] = e; }
    if (i1 < BINS) { bin_base[i1] = e + c0; bin_cursor[i1] = e + c0; }
    if (tid == 0) bin_base[BINS] = E_total;
}

// ---- pass 1: block-local counting sort by bin, coalesced write to pool ----
// entry: lo = (row_local<<18) | gidx  (row_local<256, gidx<150K<2^18), hi = val bits
__global__ __launch_bounds__(512) void binsort(const int* __restrict__ rows,
                                               const int* __restrict__ cols,
                                               const float* __restrict__ vals, int E,
                                               int bucket_base, int gidx_base,
                                               int* __restrict__ bin_cursor,
                                               uint2* __restrict__ pool) {
    __shared__ uint2 sorted[SORT_EDGES];
    __shared__ unsigned short sbin[SORT_EDGES];
    __shared__ int hist[BINS_PAD];
    __shared__ int lscan[BINS_PAD];
    __shared__ int lcur[BINS_PAD];
    __shared__ int wsum[8], woff[8];

    int tid = threadIdx.x, lane = tid & 63, wid = tid >> 6;
    for (int i = tid; i < BINS_PAD; i += 512) { hist[i] = 0; lcur[i] = 0; }
    __syncthreads();

    int start = blockIdx.x * SORT_EDGES;
    int myb[8]; unsigned mylo[8]; float myv[8];
#pragma unroll
    for (int j = 0; j < 8; ++j) {
        int e = start + j * 512 + tid;
        if (e < E) {
            int bucket = bucket_base + rows[e];
            int gidx = gidx_base + cols[e];
            myb[j] = bucket >> BIN_ROWS_LOG;
            mylo[j] = ((unsigned)(bucket & (BIN_ROWS - 1)) << 18) | (unsigned)gidx;
            myv[j] = vals[e];
            atomicAdd(&hist[myb[j]], 1);
        } else myb[j] = -1;
    }
    __syncthreads();

    int s0 = 3 * tid, s1 = s0 + 1, s2 = s0 + 2;
    int h0 = hist[s0], h1 = hist[s1], h2 = hist[s2];
    int v = h0 + h1 + h2;
    int incl = wave_incl_scan(v, lane);
    if (lane == 63) wsum[wid] = incl;
    __syncthreads();
    if (wid == 0 && lane < 8) {
        int s = wsum[lane], si = s;
#pragma unroll
        for (int off = 1; off < 8; off <<= 1) {
            int t = __shfl_up(si, off, 64);
            if (lane >= off) si += t;
        }
        woff[lane] = si - s;
    }
    __syncthreads();
    int e0 = incl - v + woff[wid];
    lscan[s0] = e0; lscan[s1] = e0 + h0; lscan[s2] = e0 + h0 + h1;
    if (s0 < BINS && h0) hist[s0] = atomicAdd(&bin_cursor[s0], h0);
    if (s1 < BINS && h1) hist[s1] = atomicAdd(&bin_cursor[s1], h1);
    if (s2 < BINS && h2) hist[s2] = atomicAdd(&bin_cursor[s2], h2);
    __syncthreads();

#pragma unroll
    for (int j = 0; j < 8; ++j) {
        if (myb[j] >= 0) {
            int p = lscan[myb[j]] + atomicAdd(&lcur[myb[j]], 1);
            sorted[p] = make_uint2(mylo[j], __float_as_uint(myv[j]));
            sbin[p] = (unsigned short)myb[j];
        }
    }
    __syncthreads();

    int cntE = min(SORT_EDGES, E - start);
    for (int pos = tid; pos < cntE; pos += 512) {
        int b = sbin[pos];
        pool[hist[b] + (pos - lscan[b])] = sorted[pos];
    }
}

// ---- pass 1b: per-bin in-place counting sort by local row + emit CSR offs ----
__global__ __launch_bounds__(512) void refine_sort(const int* __restrict__ bin_base,
                                                   uint2* __restrict__ pool,
                                                   int* __restrict__ offs) {
    __shared__ uint2 ent[CAP];        // 48 KB
    __shared__ int rhist[BIN_ROWS];
    __shared__ int rbase[BIN_ROWS];
    __shared__ int wsum[4];
    int tid = threadIdx.x, lane = tid & 63, wid = tid >> 6;
    int b = blockIdx.x;
    int s = bin_base[b], e = bin_base[b + 1];
    int cnt = min(e - s, CAP);  // overflow statistically impossible; clamp for safety

    if (tid < BIN_ROWS) rhist[tid] = 0;
    __syncthreads();
    for (int i = tid; i < cnt; i += 512) {
        uint2 p = pool[s + i];
        ent[i] = p;
        atomicAdd(&rhist[p.x >> 18], 1);
    }
    __syncthreads();

    int v = 0, incl = 0;
    if (tid < BIN_ROWS) {
        v = rhist[tid];
        incl = wave_incl_scan(v, lane);
        if (lane == 63) wsum[wid] = incl;
    }
    __syncthreads();
    if (tid < BIN_ROWS) {
        int off = 0;
#pragma unroll
        for (int w = 0; w < 4; ++w)
            if (w < wid) off += wsum[w];
        int startp = s + (incl - v) + off;
        long long row = (long long)b * BIN_ROWS + tid;
        if (row < NB) offs[row] = startp;
        rbase[tid] = startp;  // becomes cursor
    }
    if (b == BINS - 1 && tid == 0) offs[NB] = e;
    __syncthreads();

    for (int i = tid; i < cnt; i += 512) {
        unsigned r = ent[i].x >> 18;
        int pos = atomicAdd(&rbase[r], 1);
        pool[pos] = ent[i];  // all writes stay within [s,e): L2-resident window
    }
}

// ---- pass 2: atomic-free accumulate, one wave per output row (high TLP) ----
__global__ void accum_kernel(const int* __restrict__ offs, const uint2* __restrict__ pool,
                             const float* __restrict__ user_emb,
                             const float* __restrict__ item_emb,
                             float* __restrict__ out) {
    int lane = threadIdx.x & 63;
    int b = blockIdx.x * (blockDim.x >> 6) + (threadIdx.x >> 6);
    if (b >= NB) return;
    int start = offs[b], end = offs[b + 1];

    auto gather = [&](unsigned gi) -> float {
        return (gi < (unsigned)U_CNT) ? user_emb[(size_t)gi * DDIM + lane]
                                      : item_emb[(size_t)(gi - U_CNT) * DDIM + lane];
    };

    float acc = 0.f;
    int k = start;
    for (; k + 4 <= end; k += 4) {
        uint2 p0 = pool[k], p1 = pool[k + 1], p2 = pool[k + 2], p3 = pool[k + 3];
        float x0 = gather(p0.x & 0x3FFFFu);
        float x1 = gather(p1.x & 0x3FFFFu);
        float x2 = gather(p2.x & 0x3FFFFu);
        float x3 = gather(p3.x & 0x3FFFFu);
        acc += __uint_as_float(p0.y) * x0;
        acc += __uint_as_float(p1.y) * x1;
        acc += __uint_as_float(p2.y) * x2;
        acc += __uint_as_float(p3.y) * x3;
    }
    for (; k < end; ++k) {
        uint2 p = pool[k];
        acc += __uint_as_float(p.y) * gather(p.x & 0x3FFFFu);
    }
    out[(size_t)b * DDIM + lane] = acc;
}

// ---------------- fallback (R1 atomic path) ----------------
__global__ void spmm_graph_kernel(const int* __restrict__ rows, const int* __restrict__ cols,
                                  const float* __restrict__ vals,
                                  const float* __restrict__ user_emb,
                                  const float* __restrict__ item_emb,
                                  float* __restrict__ out, int E) {
    long long idx = (long long)blockIdx.x * blockDim.x + threadIdx.x;
    int e = (int)(idx >> 6), d = (int)(idx & 63);
    if (e >= E) return;
    int r = rows[e], c = cols[e];
    float v = vals[e];
    float x = (c < U_CNT) ? user_emb[(long long)c * DDIM + d]
                          : item_emb[(long long)(c - U_CNT) * DDIM + d];
    atomicAdd(&out[(long long)r * DDIM + d], v * x);
}

__global__ void spmm_plain_kernel(const int* __restrict__ rows, const int* __restrict__ cols,
                                  const float* __restrict__ vals,
                                  const float* __restrict__ emb,
                                  float* __restrict__ out, int E) {
    long long idx = (long long)blockIdx.x * blockDim.x + threadIdx.x;
    int e = (int)(idx >> 6), d = (int)(idx & 63);
    if (e >= E) return;
    int r = rows[e], c = cols[e];
    atomicAdd(&out[(long long)r * DDIM + d], vals[e] * emb[(long long)c * DDIM + d]);
}

// ---------------- launch ----------------
extern "C" void kernel_launch(void* const* d_in, const int* in_sizes, int n_in,
                              void* d_out, int out_size, void* d_ws, size_t ws_size,
                              hipStream_t stream) {
    const float* user_emb = (const float*)d_in[0];
    const float* item_emb = (const float*)d_in[1];
    const int*   g_rows   = (const int*)d_in[2];
    const int*   g_cols   = (const int*)d_in[3];
    const float* g_vals   = (const float*)d_in[4];
    const int*   u_rows   = (const int*)d_in[5];
    const int*   u_cols   = (const int*)d_in[6];
    const float* u_vals   = (const float*)d_in[7];
    const int*   i_rows   = (const int*)d_in[8];
    const int*   i_cols   = (const int*)d_in[9];
    const float* i_vals   = (const float*)d_in[10];
    float* out = (float*)d_out;

    const int EG = in_sizes[2];
    const int EU = in_sizes[5];
    const int EI = in_sizes[8];
    const int Et = EG + EU + EI;

    // ws: cnt[BINS_PAD] | bin_base[BINS+1] | bin_cursor[BINS] | offs[NB+1] | pool[Et]
    size_t off_base   = (size_t)BINS_PAD * sizeof(int);
    size_t off_cursor = off_base + (size_t)(BINS + 1) * sizeof(int);
    size_t off_offs   = off_cursor + (size_t)BINS * sizeof(int);
    size_t off_pool   = (off_offs + (size_t)(NB + 1) * sizeof(int) + 15) & ~(size_t)15;
    size_t needed     = off_pool + (size_t)Et * sizeof(uint2);

    if (ws_size >= needed) {
        int*   cnt        = (int*)d_ws;
        int*   bin_base   = (int*)((char*)d_ws + off_base);
        int*   bin_cursor = (int*)((char*)d_ws + off_cursor);
        int*   offs       = (int*)((char*)d_ws + off_offs);
        uint2* pool       = (uint2*)((char*)d_ws + off_pool);

        hipMemsetAsync(cnt, 0, (size_t)BINS_PAD * sizeof(int), stream);

        unsigned hblocks = (unsigned)((Et + HIST_EDGES - 1) / HIST_EDGES);
        hist_pre<<<hblocks, 1024, 0, stream>>>(g_rows, u_rows, i_rows, EG, EU, EI, cnt);
        scan_bins<<<1, 1024, 0, stream>>>(cnt, bin_base, bin_cursor, Et);

        unsigned gb = (unsigned)((EG + SORT_EDGES - 1) / SORT_EDGES);
        unsigned ub = (unsigned)((EU + SORT_EDGES - 1) / SORT_EDGES);
        unsigned ib = (unsigned)((EI + SORT_EDGES - 1) / SORT_EDGES);
        binsort<<<gb, 512, 0, stream>>>(g_rows, g_cols, g_vals, EG, 0,             0,     bin_cursor, pool);
        binsort<<<ub, 512, 0, stream>>>(u_rows, u_cols, u_vals, EU, N_CNT,         0,     bin_cursor, pool);
        binsort<<<ib, 512, 0, stream>>>(i_rows, i_cols, i_vals, EI, N_CNT + U_CNT, U_CNT, bin_cursor, pool);

        refine_sort<<<BINS, 512, 0, stream>>>(bin_base, pool, offs);

        unsigned ablocks = (unsigned)((NB + 3) / 4);  // 4 rows/block (256 thr)
        accum_kernel<<<ablocks, 256, 0, stream>>>(offs, pool, user_emb, item_emb, out);
    } else {
        hipMemsetAsync(d_out, 0, (size_t)out_size * sizeof(float), stream);
        const int block = 256;
        {
            long long t = (long long)EG * DDIM;
            spmm_graph_kernel<<<(unsigned)((t + block - 1) / block), block, 0, stream>>>(
                g_rows, g_cols, g_vals, user_emb, item_emb, out, EG);
        }
        {
            long long t = (long long)EU * DDIM;
            spmm_plain_kernel<<<(unsigned)((t + block - 1) / block), block, 0, stream>>>(
                u_rows, u_cols, u_vals, user_emb, out + (size_t)N_CNT * DDIM, EU);
        }
        {
            long long t = (long long)EI * DDIM;
            spmm_plain_kernel<<<(unsigned)((t + block - 1) / block), block, 0, stream>>>(
                i_rows, i_cols, i_vals, item_emb, out + (size_t)(N_CNT + U_CNT) * DDIM, EI);
        }
    }
}

// Round 5
// 463.274 us; speedup vs baseline: 4.2148x; 1.1291x over previous
//
#include <hip/hip_runtime.h>

#define DDIM 64
constexpr int U_CNT = 100000;
constexpr int I_CNT = 50000;
constexpr int N_CNT = U_CNT + I_CNT;          // 150000
constexpr int NB    = N_CNT + U_CNT + I_CNT;  // 300000 output rows

constexpr int BIN_ROWS_LOG = 8;
constexpr int BIN_ROWS = 1 << BIN_ROWS_LOG;               // 256 rows / bin
constexpr int BINS = (NB + BIN_ROWS - 1) / BIN_ROWS;      // 1172
constexpr int BINS_PAD = 1536;                            // 512 thr * 3 slots
constexpr int SORT_EDGES = 4096;                          // edges per binsort block
constexpr int HIST_EDGES = 8192;                          // edges per hist block
constexpr int CAP = 6144;  // max edges/bin (mean 4096, sigma ~64)

__device__ __forceinline__ int wave_incl_scan(int v, int lane) {
#pragma unroll
    for (int off = 1; off < 64; off <<= 1) {
        int t = __shfl_up(v, off, 64);
        if (lane >= off) v += t;
    }
    return v;
}

__device__ __forceinline__ unsigned short f2bf_rne(float f) {
    unsigned u = __float_as_uint(f);
    unsigned r = (u + 0x7FFFu + ((u >> 16) & 1u)) >> 16;
    return (unsigned short)r;
}

// ---- prepass: concat + convert embeddings to bf16 table ----
__global__ __launch_bounds__(256) void convert_emb(const float* __restrict__ ue,
                                                   const float* __restrict__ ie,
                                                   unsigned short* __restrict__ emb16) {
    int g = blockIdx.x * 256 + threadIdx.x;          // float4 group id
    constexpr int UG = U_CNT * (DDIM / 4);           // 1.6M groups
    constexpr int TG = N_CNT * (DDIM / 4);           // 2.4M groups
    if (g >= TG) return;
    float4 v = (g < UG) ? ((const float4*)ue)[g] : ((const float4*)ie)[g - UG];
    ushort4 o;
    o.x = f2bf_rne(v.x); o.y = f2bf_rne(v.y); o.z = f2bf_rne(v.z); o.w = f2bf_rne(v.w);
    ((ushort4*)emb16)[g] = o;
}

// ---- pass 0: coarse histogram over bins ----
__global__ __launch_bounds__(1024) void hist_pre(const int* __restrict__ gr,
                                                 const int* __restrict__ ur,
                                                 const int* __restrict__ ir,
                                                 int EG, int EU, int EI,
                                                 int* __restrict__ cnt) {
    __shared__ int h[BINS_PAD];
    for (int i = threadIdx.x; i < BINS_PAD; i += 1024) h[i] = 0;
    __syncthreads();
    int base = blockIdx.x * HIST_EDGES;
    int Et = EG + EU + EI;
#pragma unroll
    for (int j = 0; j < 8; ++j) {
        int e = base + j * 1024 + threadIdx.x;
        if (e < Et) {
            int b;
            if (e < EG)           b = gr[e];
            else if (e < EG + EU) b = N_CNT + ur[e - EG];
            else                  b = N_CNT + U_CNT + ir[e - EG - EU];
            atomicAdd(&h[b >> BIN_ROWS_LOG], 1);
        }
    }
    __syncthreads();
    for (int i = threadIdx.x; i < BINS; i += 1024) {
        int v = h[i];
        if (v) atomicAdd(&cnt[i], v);
    }
}

// ---- pass 0b: exclusive scan of bin counts (single block) ----
__global__ __launch_bounds__(1024) void scan_bins(const int* __restrict__ cnt,
                                                  int* __restrict__ bin_base,
                                                  int* __restrict__ bin_cursor,
                                                  int E_total) {
    __shared__ int wsum[16], woff[16];
    int tid = threadIdx.x, lane = tid & 63, wid = tid >> 6;
    int i0 = 2 * tid, i1 = 2 * tid + 1;
    int c0 = (i0 < BINS) ? cnt[i0] : 0;
    int c1 = (i1 < BINS) ? cnt[i1] : 0;
    int v = c0 + c1;
    int incl = wave_incl_scan(v, lane);
    if (lane == 63) wsum[wid] = incl;
    __syncthreads();
    if (wid == 0 && lane < 16) {
        int s = wsum[lane], si = s;
#pragma unroll
        for (int off = 1; off < 16; off <<= 1) {
            int t = __shfl_up(si, off, 64);
            if (lane >= off) si += t;
        }
        woff[lane] = si - s;
    }
    __syncthreads();
    int e = incl - v + woff[wid];
    if (i0 < BINS) { bin_base[i0] = e;      bin_cursor[i0] = e; }
    if (i1 < BINS) { bin_base[i1] = e + c0; bin_cursor[i1] = e + c0; }
    if (tid == 0) bin_base[BINS] = E_total;
}

// ---- pass 1: block-local counting sort by bin, coalesced write to pool ----
// entry: lo = (row_local<<18) | gidx  (row_local<256, gidx<150K<2^18), hi = val bits
__global__ __launch_bounds__(512) void binsort(const int* __restrict__ rows,
                                               const int* __restrict__ cols,
                                               const float* __restrict__ vals, int E,
                                               int bucket_base, int gidx_base,
                                               int* __restrict__ bin_cursor,
                                               uint2* __restrict__ pool) {
    __shared__ uint2 sorted[SORT_EDGES];
    __shared__ unsigned short sbin[SORT_EDGES];
    __shared__ int hist[BINS_PAD];
    __shared__ int lscan[BINS_PAD];
    __shared__ int lcur[BINS_PAD];
    __shared__ int wsum[8], woff[8];

    int tid = threadIdx.x, lane = tid & 63, wid = tid >> 6;
    for (int i = tid; i < BINS_PAD; i += 512) { hist[i] = 0; lcur[i] = 0; }
    __syncthreads();

    int start = blockIdx.x * SORT_EDGES;
    int base_e = start + tid * 8;  // 8 consecutive edges per thread, 16B-aligned
    int myb[8]; unsigned mylo[8]; float myv[8];
#pragma unroll
    for (int j = 0; j < 8; j += 4) {
        int e = base_e + j;
        if (e + 3 < E) {
            int4   r4 = *(const int4*)(rows + e);
            int4   c4 = *(const int4*)(cols + e);
            float4 v4 = *(const float4*)(vals + e);
            int rr[4] = {r4.x, r4.y, r4.z, r4.w};
            int cc[4] = {c4.x, c4.y, c4.z, c4.w};
            float vv[4] = {v4.x, v4.y, v4.z, v4.w};
#pragma unroll
            for (int q = 0; q < 4; ++q) {
                int bucket = bucket_base + rr[q];
                myb[j + q] = bucket >> BIN_ROWS_LOG;
                mylo[j + q] = ((unsigned)(bucket & (BIN_ROWS - 1)) << 18) |
                              (unsigned)(gidx_base + cc[q]);
                myv[j + q] = vv[q];
                atomicAdd(&hist[myb[j + q]], 1);
            }
        } else {
#pragma unroll
            for (int q = 0; q < 4; ++q) {
                int ee = e + q;
                if (ee < E) {
                    int bucket = bucket_base + rows[ee];
                    myb[j + q] = bucket >> BIN_ROWS_LOG;
                    mylo[j + q] = ((unsigned)(bucket & (BIN_ROWS - 1)) << 18) |
                                  (unsigned)(gidx_base + cols[ee]);
                    myv[j + q] = vals[ee];
                    atomicAdd(&hist[myb[j + q]], 1);
                } else myb[j + q] = -1;
            }
        }
    }
    __syncthreads();

    int s0 = 3 * tid, s1 = s0 + 1, s2 = s0 + 2;
    int h0 = hist[s0], h1 = hist[s1], h2 = hist[s2];
    int v = h0 + h1 + h2;
    int incl = wave_incl_scan(v, lane);
    if (lane == 63) wsum[wid] = incl;
    __syncthreads();
    if (wid == 0 && lane < 8) {
        int s = wsum[lane], si = s;
#pragma unroll
        for (int off = 1; off < 8; off <<= 1) {
            int t = __shfl_up(si, off, 64);
            if (lane >= off) si += t;
        }
        woff[lane] = si - s;
    }
    __syncthreads();
    int e0 = incl - v + woff[wid];
    lscan[s0] = e0; lscan[s1] = e0 + h0; lscan[s2] = e0 + h0 + h1;
    if (s0 < BINS && h0) hist[s0] = atomicAdd(&bin_cursor[s0], h0);
    if (s1 < BINS && h1) hist[s1] = atomicAdd(&bin_cursor[s1], h1);
    if (s2 < BINS && h2) hist[s2] = atomicAdd(&bin_cursor[s2], h2);
    __syncthreads();

#pragma unroll
    for (int j = 0; j < 8; ++j) {
        if (myb[j] >= 0) {
            int p = lscan[myb[j]] + atomicAdd(&lcur[myb[j]], 1);
            sorted[p] = make_uint2(mylo[j], __float_as_uint(myv[j]));
            sbin[p] = (unsigned short)myb[j];
        }
    }
    __syncthreads();

    int cntE = min(SORT_EDGES, E - start);
    for (int pos = tid; pos < cntE; pos += 512) {
        int b = sbin[pos];
        pool[hist[b] + (pos - lscan[b])] = sorted[pos];
    }
}

// ---- pass 2 (fused): per-bin LDS row-sort + wave-per-row accumulate ----
template <bool BF16>
__global__ __launch_bounds__(512) void refine_accum(const int* __restrict__ bin_base,
                                                    const uint2* __restrict__ pool,
                                                    const unsigned short* __restrict__ emb16,
                                                    const float* __restrict__ ue,
                                                    const float* __restrict__ ie,
                                                    float* __restrict__ out) {
    __shared__ uint2 sorted[CAP];     // 48 KB
    __shared__ int rhist[BIN_ROWS];
    __shared__ int rstart[BIN_ROWS];
    __shared__ int rcur[BIN_ROWS];
    __shared__ int wsum[4];
    int tid = threadIdx.x, lane = tid & 63, wid = tid >> 6;  // 8 waves
    int b = blockIdx.x;
    int s = bin_base[b], e = bin_base[b + 1];
    int cnt = min(e - s, CAP);

    if (tid < BIN_ROWS) rhist[tid] = 0;
    __syncthreads();

    // pass A: row histogram (read only .x words)
    const unsigned* px = (const unsigned*)pool;
    for (int i = tid; i < cnt; i += 512)
        atomicAdd(&rhist[px[2 * (size_t)(s + i)] >> 18], 1);
    __syncthreads();

    // scan 256 row counts with waves 0..3
    int v = 0, incl = 0;
    if (tid < BIN_ROWS) {
        v = rhist[tid];
        incl = wave_incl_scan(v, lane);
        if (lane == 63) wsum[wid] = incl;
    }
    __syncthreads();
    if (tid < BIN_ROWS) {
        int off = 0;
#pragma unroll
        for (int w = 0; w < 4; ++w)
            if (w < wid) off += wsum[w];
        int st = incl - v + off;
        rstart[tid] = st; rcur[tid] = st;
    }
    __syncthreads();

    // pass B: re-read (L2-hot) and scatter row-sorted into LDS
    for (int i = tid; i < cnt; i += 512) {
        uint2 p = pool[s + i];
        int pos = atomicAdd(&rcur[p.x >> 18], 1);
        sorted[pos] = p;
    }
    __syncthreads();

    // accumulate: wave per row, entries broadcast from LDS, gather from global
    long long rowbase = (long long)b * BIN_ROWS;
    auto gather = [&](unsigned gi) -> float {
        if (BF16) return __uint_as_float((unsigned)emb16[((size_t)gi << 6) + lane] << 16);
        return (gi < (unsigned)U_CNT) ? ue[((size_t)gi << 6) + lane]
                                      : ie[(((size_t)gi - U_CNT) << 6) + lane];
    };
    for (int r = wid; r < BIN_ROWS; r += 8) {
        long long row = rowbase + r;
        if (row >= NB) break;
        int k = rstart[r], ke = k + rhist[r];
        float acc = 0.f;
        for (; k + 4 <= ke; k += 4) {
            uint2 p0 = sorted[k], p1 = sorted[k + 1], p2 = sorted[k + 2], p3 = sorted[k + 3];
            float x0 = gather(p0.x & 0x3FFFFu);
            float x1 = gather(p1.x & 0x3FFFFu);
            float x2 = gather(p2.x & 0x3FFFFu);
            float x3 = gather(p3.x & 0x3FFFFu);
            acc += __uint_as_float(p0.y) * x0;
            acc += __uint_as_float(p1.y) * x1;
            acc += __uint_as_float(p2.y) * x2;
            acc += __uint_as_float(p3.y) * x3;
        }
        for (; k < ke; ++k) {
            uint2 p = sorted[k];
            acc += __uint_as_float(p.y) * gather(p.x & 0x3FFFFu);
        }
        out[(size_t)row * DDIM + lane] = acc;
    }
}

// ---------------- fallback (R1 atomic path) ----------------
__global__ void spmm_graph_kernel(const int* __restrict__ rows, const int* __restrict__ cols,
                                  const float* __restrict__ vals,
                                  const float* __restrict__ user_emb,
                                  const float* __restrict__ item_emb,
                                  float* __restrict__ out, int E) {
    long long idx = (long long)blockIdx.x * blockDim.x + threadIdx.x;
    int e = (int)(idx >> 6), d = (int)(idx & 63);
    if (e >= E) return;
    int r = rows[e], c = cols[e];
    float v = vals[e];
    float x = (c < U_CNT) ? user_emb[(long long)c * DDIM + d]
                          : item_emb[(long long)(c - U_CNT) * DDIM + d];
    atomicAdd(&out[(long long)r * DDIM + d], v * x);
}

__global__ void spmm_plain_kernel(const int* __restrict__ rows, const int* __restrict__ cols,
                                  const float* __restrict__ vals,
                                  const float* __restrict__ emb,
                                  float* __restrict__ out, int E) {
    long long idx = (long long)blockIdx.x * blockDim.x + threadIdx.x;
    int e = (int)(idx >> 6), d = (int)(idx & 63);
    if (e >= E) return;
    int r = rows[e], c = cols[e];
    atomicAdd(&out[(long long)r * DDIM + d], vals[e] * emb[(long long)c * DDIM + d]);
}

// ---------------- launch ----------------
extern "C" void kernel_launch(void* const* d_in, const int* in_sizes, int n_in,
                              void* d_out, int out_size, void* d_ws, size_t ws_size,
                              hipStream_t stream) {
    const float* user_emb = (const float*)d_in[0];
    const float* item_emb = (const float*)d_in[1];
    const int*   g_rows   = (const int*)d_in[2];
    const int*   g_cols   = (const int*)d_in[3];
    const float* g_vals   = (const float*)d_in[4];
    const int*   u_rows   = (const int*)d_in[5];
    const int*   u_cols   = (const int*)d_in[6];
    const float* u_vals   = (const float*)d_in[7];
    const int*   i_rows   = (const int*)d_in[8];
    const int*   i_cols   = (const int*)d_in[9];
    const float* i_vals   = (const float*)d_in[10];
    float* out = (float*)d_out;

    const int EG = in_sizes[2];
    const int EU = in_sizes[5];
    const int EI = in_sizes[8];
    const int Et = EG + EU + EI;

    // ws: cnt[BINS_PAD] | bin_base[BINS+1] | bin_cursor[BINS] | pool[Et] | emb16[N*64]
    size_t off_base   = (size_t)BINS_PAD * sizeof(int);
    size_t off_cursor = off_base + (size_t)(BINS + 1) * sizeof(int);
    size_t off_pool   = (off_cursor + (size_t)BINS * sizeof(int) + 15) & ~(size_t)15;
    size_t off_emb    = off_pool + (size_t)Et * sizeof(uint2);
    size_t needed_min  = off_emb;
    size_t needed_full = off_emb + (size_t)N_CNT * DDIM * sizeof(unsigned short);

    if (ws_size >= needed_min) {
        int*   cnt        = (int*)d_ws;
        int*   bin_base   = (int*)((char*)d_ws + off_base);
        int*   bin_cursor = (int*)((char*)d_ws + off_cursor);
        uint2* pool       = (uint2*)((char*)d_ws + off_pool);
        unsigned short* emb16 = (unsigned short*)((char*)d_ws + off_emb);
        bool use_bf16 = (ws_size >= needed_full);

        hipMemsetAsync(cnt, 0, (size_t)BINS_PAD * sizeof(int), stream);

        if (use_bf16) {
            unsigned cgrid = (unsigned)((N_CNT * (DDIM / 4) + 255) / 256);
            convert_emb<<<cgrid, 256, 0, stream>>>(user_emb, item_emb, emb16);
        }

        unsigned hblocks = (unsigned)((Et + HIST_EDGES - 1) / HIST_EDGES);
        hist_pre<<<hblocks, 1024, 0, stream>>>(g_rows, u_rows, i_rows, EG, EU, EI, cnt);
        scan_bins<<<1, 1024, 0, stream>>>(cnt, bin_base, bin_cursor, Et);

        unsigned gb = (unsigned)((EG + SORT_EDGES - 1) / SORT_EDGES);
        unsigned ub = (unsigned)((EU + SORT_EDGES - 1) / SORT_EDGES);
        unsigned ib = (unsigned)((EI + SORT_EDGES - 1) / SORT_EDGES);
        binsort<<<gb, 512, 0, stream>>>(g_rows, g_cols, g_vals, EG, 0,             0,     bin_cursor, pool);
        binsort<<<ub, 512, 0, stream>>>(u_rows, u_cols, u_vals, EU, N_CNT,         0,     bin_cursor, pool);
        binsort<<<ib, 512, 0, stream>>>(i_rows, i_cols, i_vals, EI, N_CNT + U_CNT, U_CNT, bin_cursor, pool);

        if (use_bf16)
            refine_accum<true><<<BINS, 512, 0, stream>>>(bin_base, pool, emb16,
                                                         user_emb, item_emb, out);
        else
            refine_accum<false><<<BINS, 512, 0, stream>>>(bin_base, pool, (const unsigned short*)nullptr,
                                                          user_emb, item_emb, out);
    } else {
        hipMemsetAsync(d_out, 0, (size_t)out_size * sizeof(float), stream);
        const int block = 256;
        {
            long long t = (long long)EG * DDIM;
            spmm_graph_kernel<<<(unsigned)((t + block - 1) / block), block, 0, stream>>>(
                g_rows, g_cols, g_vals, user_emb, item_emb, out, EG);
        }
        {
            long long t = (long long)EU * DDIM;
            spmm_plain_kernel<<<(unsigned)((t + block - 1) / block), block, 0, stream>>>(
                u_rows, u_cols, u_vals, user_emb, out + (size_t)N_CNT * DDIM, EU);
        }
        {
            long long t = (long long)EI * DDIM;
            spmm_plain_kernel<<<(unsigned)((t + block - 1) / block), block, 0, stream>>>(
                i_rows, i_cols, i_vals, item_emb, out + (size_t)(N_CNT + U_CNT) * DDIM, EI);
        }
    }
}